// Round 1
// baseline (164.495 us; speedup 1.0000x reference)
//
#include <hip/hip_runtime.h>
#include <hip/hip_bf16.h>

typedef __attribute__((ext_vector_type(8))) short short8;   // 8 x bf16 (4 VGPRs)
typedef __attribute__((ext_vector_type(4))) float floatx4;  // MFMA acc

#define XS_STRIDE 72    // ushorts; xs[204][72] = 29376 B at smem+0, DEAD after A2a frag preload
// ys: bf16 [204 px][128 c], 256 B rows, XOR-swizzled: phys_byte = px*256 + ((c*2) ^ ((px&7)<<5))
//     52224 B at smem+0 (time-overlays xs; A-frags preloaded to regs behind a barrier)
// ostage: f32 [16][132] = 8448 B, placed in the DEAD ys band of pixel-row oy (offset oy*8704,
//     8704 B per band). Two 16-pixel half-passes per oy keep output f32-exact.
// LDS total 52224 B -> 3 blocks/CU (was 81600 -> 2 blocks/CU)

__device__ __forceinline__ ushort f2bf(float f) {
    union { __hip_bfloat16 h; ushort u; } cv;
    cv.h = __float2bfloat16(f);
    return cv.u;
}
__device__ __forceinline__ float bflo(unsigned int u) { return __uint_as_float(u << 16); }
__device__ __forceinline__ float bfhi(unsigned int u) { return __uint_as_float(u & 0xffff0000u); }

__device__ __forceinline__ float dot8(uint4 p, const float* cf) {
    return bflo(p.x)*cf[0] + bfhi(p.x)*cf[1] + bflo(p.y)*cf[2] + bfhi(p.y)*cf[3]
         + bflo(p.z)*cf[4] + bfhi(p.z)*cf[5] + bflo(p.w)*cf[6] + bfhi(p.w)*cf[7];
}
__device__ __forceinline__ void fma8(uint4 p, float a, float* o) {
    o[0] += a*bflo(p.x); o[1] += a*bfhi(p.x); o[2] += a*bflo(p.y); o[3] += a*bfhi(p.y);
    o[4] += a*bflo(p.z); o[5] += a*bfhi(p.z); o[6] += a*bflo(p.w); o[7] += a*bfhi(p.w);
}

// sum over the 8 lanes sharing a pixel (lane bits 0..2): xor1/xor2 on the VALU pipe via
// DPP quad_perm (phase B is LDS-pipe-heavy; keep the reduce off lgkm), xor4 via shfl.
__device__ __forceinline__ float gsum8(float v) {
    v += __int_as_float(__builtin_amdgcn_update_dpp(0, __float_as_int(v), 0xB1, 0xF, 0xF, false)); // xor1
    v += __int_as_float(__builtin_amdgcn_update_dpp(0, __float_as_int(v), 0x4E, 0xF, 0xF, false)); // xor2
    v += __shfl_xor(v, 4);                                                                          // xor4
    return v;
}

__global__ __launch_bounds__(256, 3)
void attn_conv_fused(const float* __restrict__ x, const float* __restrict__ Wc,
                     const float* __restrict__ bc, float* __restrict__ out) {
    __shared__ __align__(16) unsigned char smem[52224];
    ushort* xs = (ushort*)smem;

    const int tid = threadIdx.x;
    // XCD-chunked swizzle (bijective, 1024 = 8*128): XCD k owns batch k entirely;
    // within an XCD, w-tiles fastest then h-bands -> halo rows stay L2-resident.
    const int rid = ((blockIdx.x & 7) << 7) | (blockIdx.x >> 3);
    const int b   = rid >> 7;
    const int h0  = ((rid >> 2) & 31) * 4;
    const int w0  = (rid & 3) * 32;
    const int lane = tid & 63;
    const int wv   = tid >> 6;

    // ---------------- Phase A0: stage x tile transposed -> xs[px][ci] bf16 ----
    if (tid < 204) {
        int py  = (tid * 965) >> 15;          // tid / 34 (exact for tid<208)
        int pxx = tid - py * 34;
        int gh = h0 + py - 1, gw = w0 + pxx - 1;
        bool inb = (gh >= 0 && gh < 128 && gw >= 0 && gw < 128);
        ushort* dst = xs + tid * XS_STRIDE;
        if (inb) {
            const float* xp = x + (b * 64) * 16384 + gh * 128 + gw;
            #pragma unroll
            for (int c0 = 0; c0 < 64; c0 += 4) {
                float v0 = xp[(c0 + 0) << 14];
                float v1 = xp[(c0 + 1) << 14];
                float v2 = xp[(c0 + 2) << 14];
                float v3 = xp[(c0 + 3) << 14];
                unsigned int u01 = (unsigned int)f2bf(v0) | ((unsigned int)f2bf(v1) << 16);
                unsigned int u23 = (unsigned int)f2bf(v2) | ((unsigned int)f2bf(v3) << 16);
                *(uint2*)(dst + c0) = make_uint2(u01, u23);
            }
        } else {
            #pragma unroll
            for (int c0 = 0; c0 < 64; c0 += 4)
                *(uint2*)(dst + c0) = make_uint2(0u, 0u);
        }
    }

    // ---------------- Phase A1: W fragments (B-operand) from global ----------
    const int col = lane & 15;
    const int kq  = lane >> 4;
    short8 bw[8][2];
    float  bias[8];
    #pragma unroll
    for (int t = 0; t < 8; ++t) {
        int c = t * 16 + col;
        bias[t] = bc[c];
        #pragma unroll
        for (int half = 0; half < 2; ++half) {
            const float* wp = Wc + c * 64 + half * 32 + kq * 8;
            float4 wa = *(const float4*)wp;
            float4 wb = *(const float4*)(wp + 4);
            short8 f;
            f[0] = (short)f2bf(wa.x); f[1] = (short)f2bf(wa.y);
            f[2] = (short)f2bf(wa.z); f[3] = (short)f2bf(wa.w);
            f[4] = (short)f2bf(wb.x); f[5] = (short)f2bf(wb.y);
            f[6] = (short)f2bf(wb.z); f[7] = (short)f2bf(wb.w);
            bw[t][half] = f;
        }
    }
    __syncthreads();

    // ---------------- Phase A2a: preload this wave's A-fragments (xs dies) ----
    short8 af0[4], af1[4];
    #pragma unroll
    for (int i = 0; i < 4; ++i) {
        int mt = wv + i * 4;
        if (mt < 13) {
            const ushort* ap = xs + (mt * 16 + col) * XS_STRIDE + kq * 8;
            af0[i] = *(const short8*)(ap);        // k 0..31
            af1[i] = *(const short8*)(ap + 32);   // k 32..63
        }
    }
    __syncthreads();   // all xs reads done; ys region (overlapping xs) now writable

    // ---------------- Phase A2b: MFMA conv -> ys bf16 (swizzled) -------------
    #pragma unroll
    for (int i = 0; i < 4; ++i) {
        int mt = wv + i * 4;
        if (mt < 13) {
            floatx4 acc[8];
            #pragma unroll
            for (int t = 0; t < 8; ++t) acc[t] = (floatx4){0.f, 0.f, 0.f, 0.f};
            #pragma unroll
            for (int t = 0; t < 8; ++t) {
                acc[t] = __builtin_amdgcn_mfma_f32_16x16x32_bf16(af0[i], bw[t][0], acc[t], 0, 0, 0);
                acc[t] = __builtin_amdgcn_mfma_f32_16x16x32_bf16(af1[i], bw[t][1], acc[t], 0, 0, 0);
            }
            #pragma unroll
            for (int r = 0; r < 4; ++r) {
                int pxr = mt * 16 + kq * 4 + r;   // D row = (lane>>4)*4 + r
                if (pxr < 204) {
                    int py  = (pxr * 965) >> 15;
                    int pxx = pxr - py * 34;
                    int gh = h0 + py - 1, gw = w0 + pxx - 1;
                    bool inb = (gh >= 0 && gh < 128 && gw >= 0 && gw < 128);
                    char* yrow = (char*)smem + pxr * 256;
                    int swz = (pxr & 7) << 5;
                    #pragma unroll
                    for (int t = 0; t < 8; ++t)
                        *(ushort*)(yrow + (((t * 32) ^ swz) + col * 2)) =
                            f2bf(inb ? (acc[t][r] + bias[t]) : 0.f);
                }
            }
        }
    }
    __syncthreads();

    // ---------------- Phase B: 3x3 local attention, one row per pass ---------
    const int g  = tid & 7;                   // channel group: c0 = g*16
    const int ox = tid >> 3;                  // 0..31
    for (int oy = 0; oy < 4; ++oy) {
        int pc = (oy + 1) * 34 + (ox + 1);
        uint4 plo[9], phi[9];
        #pragma unroll
        for (int n = 0; n < 9; ++n) {
            int pi = pc + (n / 3 - 1) * 34 + (n % 3 - 1);
            const char* pp = (const char*)smem + pi * 256 + ((g * 32) ^ ((pi & 7) << 5));
            plo[n] = *(const uint4*)pp;
            phi[n] = *(const uint4*)(pp + 16);
        }
        float cf[16];
        {
            uint4 c0 = plo[4], c1 = phi[4];
            cf[0]=bflo(c0.x); cf[1]=bfhi(c0.x); cf[2]=bflo(c0.y); cf[3]=bfhi(c0.y);
            cf[4]=bflo(c0.z); cf[5]=bfhi(c0.z); cf[6]=bflo(c0.w); cf[7]=bfhi(c0.w);
            cf[8]=bflo(c1.x); cf[9]=bfhi(c1.x); cf[10]=bflo(c1.y); cf[11]=bfhi(c1.y);
            cf[12]=bflo(c1.z); cf[13]=bfhi(c1.z); cf[14]=bflo(c1.w); cf[15]=bfhi(c1.w);
        }
        float s[9];
        #pragma unroll
        for (int n = 0; n < 9; ++n)
            s[n] = dot8(plo[n], cf) + dot8(phi[n], cf + 8);
        #pragma unroll
        for (int n = 0; n < 9; ++n)
            s[n] = gsum8(s[n]) * 0.08838834764831845f;    // 1/sqrt(128)
        float m = s[0];
        #pragma unroll
        for (int n = 1; n < 9; ++n) m = fmaxf(m, s[n]);
        float e[9], sum = 0.f;
        #pragma unroll
        for (int n = 0; n < 9; ++n) { e[n] = __expf(s[n] - m); sum += e[n]; }
        float inv = 1.f / sum;

        float o[16];
        #pragma unroll
        for (int j = 0; j < 16; ++j) o[j] = 0.f;
        #pragma unroll
        for (int n = 0; n < 9; ++n) {
            float a = e[n] * inv;
            fma8(plo[n], a, o);
            fma8(phi[n], a, o + 8);
        }

        // ---- store via f32 restage in the now-dead ys band `oy` (two 16-px passes)
        float* ost = (float*)((char*)smem + oy * 8704);
        __syncthreads();                       // all ys band-oy reads complete
        if (ox < 16) {
            float* op = ost + ox * 132 + g * 16;
            #pragma unroll
            for (int k = 0; k < 4; ++k)
                *(float4*)(op + 4 * k) = make_float4(o[4*k], o[4*k+1], o[4*k+2], o[4*k+3]);
        }
        __syncthreads();
        {
            int c = tid >> 1, q = tid & 1;
            float tmp[8];
            #pragma unroll
            for (int j = 0; j < 8; ++j) tmp[j] = ost[(q * 8 + j) * 132 + c];
            float* og = out + ((size_t)((b * 128 + c) * 128 + (h0 + oy))) * 128 + w0 + q * 8;
            *(float4*)og       = make_float4(tmp[0], tmp[1], tmp[2], tmp[3]);
            *(float4*)(og + 4) = make_float4(tmp[4], tmp[5], tmp[6], tmp[7]);
        }
        __syncthreads();
        if (ox >= 16) {
            float* op = ost + (ox - 16) * 132 + g * 16;
            #pragma unroll
            for (int k = 0; k < 4; ++k)
                *(float4*)(op + 4 * k) = make_float4(o[4*k], o[4*k+1], o[4*k+2], o[4*k+3]);
        }
        __syncthreads();
        {
            int c = tid >> 1, q = tid & 1;
            float tmp[8];
            #pragma unroll
            for (int j = 0; j < 8; ++j) tmp[j] = ost[(q * 8 + j) * 132 + c];
            float* og = out + ((size_t)((b * 128 + c) * 128 + (h0 + oy))) * 128 + w0 + 16 + q * 8;
            *(float4*)og       = make_float4(tmp[0], tmp[1], tmp[2], tmp[3]);
            *(float4*)(og + 4) = make_float4(tmp[4], tmp[5], tmp[6], tmp[7]);
        }
        // no barrier needed before next oy: next compute reads ys rows > band oy,
        // disjoint from this ostage region; next ostage write is behind next b1.
    }
}

extern "C" void kernel_launch(void* const* d_in, const int* in_sizes, int n_in,
                              void* d_out, int out_size, void* d_ws, size_t ws_size,
                              hipStream_t stream) {
    const float* x  = (const float*)d_in[0];
    const float* Wc = (const float*)d_in[1];
    const float* bc = (const float*)d_in[2];
    float* out = (float*)d_out;

    dim3 grid(1024);         // flat; XCD-chunked decode in-kernel
    dim3 block(256);
    attn_conv_fused<<<grid, block, 0, stream>>>(x, Wc, bc, out);
}